// Round 2
// baseline (185.202 us; speedup 1.0000x reference)
//
#include <hip/hip_runtime.h>

typedef __attribute__((ext_vector_type(4))) float f32x4;
typedef __attribute__((ext_vector_type(8))) short bf16x8;
typedef __attribute__((ext_vector_type(4))) short bf16x4;

#define D 128
#define BM 64

__device__ __forceinline__ unsigned short f2bf(float f){
  union { float f; unsigned int i; } c; c.f = f;
  unsigned int i = c.i;
  i += 0x7fffu + ((i >> 16) & 1u);   // round-to-nearest-even
  return (unsigned short)(i >> 16);
}
__device__ __forceinline__ float bf2f(unsigned short u){
  union { float f; unsigned int i; } c; c.i = ((unsigned int)u) << 16; return c.f;
}
__device__ __forceinline__ float sigmoid_f(float t){
  return 1.0f / (1.0f + __expf(-t));
}
__device__ __forceinline__ float tanh_f(float t){
  t = fminf(fmaxf(t, -20.0f), 20.0f);
  float e = __expf(2.0f * t);
  return (e - 1.0f) / (e + 1.0f);
}

// Pack W[k=256][n=128] fp32 -> bf16 MFMA B-fragments:
// frag f = nf*8+kk ; lane l holds col = nf*16+(l&15), k = kk*32+(l>>4)*8+j (j=0..7)
__global__ void prep_weights(const float* __restrict__ Wr, const float* __restrict__ Wz,
                             const float* __restrict__ Wh, unsigned short* __restrict__ wp)
{
  int w = blockIdx.x >> 6;          // 0:Wr 1:Wz 2:Wh
  int f = blockIdx.x & 63;          // nf*8 + kk
  int l = threadIdx.x;              // 0..63
  const float* src = (w == 0) ? Wr : ((w == 1) ? Wz : Wh);
  int nf = f >> 3, kk = f & 7;
  int col = nf * 16 + (l & 15);
  int k0  = kk * 32 + (l >> 4) * 8;
  unsigned short* dst = wp + w * 32768 + (f * 64 + l) * 8;
#pragma unroll
  for (int j = 0; j < 8; ++j)
    dst[j] = f2bf(src[(k0 + j) * D + col]);
}

__global__ __launch_bounds__(256, 4) void gru_fused(
    const float* __restrict__ x, const float* __restrict__ h,
    const float* __restrict__ brp, const float* __restrict__ bzp, const float* __restrict__ bhp,
    const unsigned short* __restrict__ wp, float* __restrict__ out)
{
  // A1: xh bf16 [64][256] swizzled (32KB). r*h_tan overwrites the h-half in place.
  // P: f32 partial row-sumsq [64][4], overlays A1 base after stage 2.
  __shared__ __align__(16) unsigned char A1[BM * 512];
  float* P = (float*)A1;

  const int tid = threadIdx.x;
  const int w   = tid >> 6;
  const int l   = tid & 63;
  const int l15 = l & 15;
  const int lq  = l >> 4;
  const size_t row0 = (size_t)blockIdx.x * BM;

  // ---------- phase 1: logmap0(x), logmap0(h) -> A1 bf16 (swizzled) ----------
  {
    const int row = tid >> 2;
    const int q   = tid & 3;
    const f32x4* xr = (const f32x4*)(x + (row0 + row) * D);
    const f32x4* hr = (const f32x4*)(h + (row0 + row) * D);
    f32x4 v[8];
    float ss = 0.f;
#pragma unroll
    for (int j = 0; j < 8; ++j){
      v[j] = xr[j * 4 + q];
      ss += v[j][0]*v[j][0] + v[j][1]*v[j][1] + v[j][2]*v[j][2] + v[j][3]*v[j][3];
    }
    ss += __shfl_xor(ss, 1, 64);
    ss += __shfl_xor(ss, 2, 64);
    float n = sqrtf(ss);
    float s = (n > 1e-20f) ? (0.5f * __logf((1.f + n) / (1.f - n)) / n) : 1.f;
#pragma unroll
    for (int j = 0; j < 8; ++j){
      unsigned int byte = (unsigned)(row * 512 + (4 * j + q) * 8) ^ (unsigned)((row & 7) << 4);
      bf16x4 pk;
      pk[0] = (short)f2bf(v[j][0] * s); pk[1] = (short)f2bf(v[j][1] * s);
      pk[2] = (short)f2bf(v[j][2] * s); pk[3] = (short)f2bf(v[j][3] * s);
      *(bf16x4*)(A1 + byte) = pk;
    }
    ss = 0.f;
#pragma unroll
    for (int j = 0; j < 8; ++j){
      v[j] = hr[j * 4 + q];
      ss += v[j][0]*v[j][0] + v[j][1]*v[j][1] + v[j][2]*v[j][2] + v[j][3]*v[j][3];
    }
    ss += __shfl_xor(ss, 1, 64);
    ss += __shfl_xor(ss, 2, 64);
    n = sqrtf(ss);
    s = (n > 1e-20f) ? (0.5f * __logf((1.f + n) / (1.f - n)) / n) : 1.f;
#pragma unroll
    for (int j = 0; j < 8; ++j){
      unsigned int byte = (unsigned)(row * 512 + 256 + (4 * j + q) * 8) ^ (unsigned)((row & 7) << 4);
      bf16x4 pk;
      pk[0] = (short)f2bf(v[j][0] * s); pk[1] = (short)f2bf(v[j][1] * s);
      pk[2] = (short)f2bf(v[j][2] * s); pk[3] = (short)f2bf(v[j][3] * s);
      *(bf16x4*)(A1 + byte) = pk;
    }
  }
  __syncthreads();   // (1) A1 populated

  // ---------- stage 1: wave w computes r,z for cols [w*32, w*32+32) ----------
  const unsigned short* pwr = wp + w * 8192;
  const unsigned short* pwz = wp + 32768 + w * 8192;

  f32x4 accr0[4], accr1[4], accz0[4], accz1[4];
#pragma unroll
  for (int m = 0; m < 4; ++m){ accr0[m] = 0; accr1[m] = 0; accz0[m] = 0; accz1[m] = 0; }

#pragma unroll 2
  for (int kk = 0; kk < 8; ++kk){
    const bf16x8 br0f = *(const bf16x8*)(pwr + kk * 512 + l * 8);
    const bf16x8 br1f = *(const bf16x8*)(pwr + 4096 + kk * 512 + l * 8);
    const bf16x8 bz0f = *(const bf16x8*)(pwz + kk * 512 + l * 8);
    const bf16x8 bz1f = *(const bf16x8*)(pwz + 4096 + kk * 512 + l * 8);
#pragma unroll
    for (int m = 0; m < 4; ++m){
      const int row = m * 16 + l15;
      unsigned int byte = (unsigned)(row * 512 + (kk * 32 + lq * 8) * 2) ^ (unsigned)((row & 7) << 4);
      const bf16x8 a = *(const bf16x8*)(A1 + byte);
      accr0[m] = __builtin_amdgcn_mfma_f32_16x16x32_bf16(a, br0f, accr0[m], 0, 0, 0);
      accr1[m] = __builtin_amdgcn_mfma_f32_16x16x32_bf16(a, br1f, accr1[m], 0, 0, 0);
      accz0[m] = __builtin_amdgcn_mfma_f32_16x16x32_bf16(a, bz0f, accz0[m], 0, 0, 0);
      accz1[m] = __builtin_amdgcn_mfma_f32_16x16x32_bf16(a, bz1f, accz1[m], 0, 0, 0);
    }
  }

  // ---------- epilogue 1: z stays in regs; h_tan stashed packed; r*h_tan -> regs ----------
  const int cb = w * 32 + l15;
  const float br0v = brp[cb], br1v = brp[cb + 16];
  const float bz0v = bzp[cb], bz1v = bzp[cb + 16];
  f32x4 zk0[4], zk1[4];
  unsigned int htp[4][4];   // packed bf16 (h_tan[cb] | h_tan[cb+16]<<16)
  unsigned int rhp[4][4];   // packed bf16 (r*h_tan[cb] | r*h_tan[cb+16]<<16)
#pragma unroll
  for (int m = 0; m < 4; ++m){
#pragma unroll
    for (int reg = 0; reg < 4; ++reg){
      const int row = m * 16 + lq * 4 + reg;
      const unsigned int swz = (unsigned)((row & 7) << 4);
      unsigned int u0 = *(const unsigned short*)(A1 + ((unsigned)(row * 512 + (128 + cb) * 2) ^ swz));
      unsigned int u1 = *(const unsigned short*)(A1 + ((unsigned)(row * 512 + (128 + cb + 16) * 2) ^ swz));
      htp[m][reg] = u0 | (u1 << 16);
      float rv0 = sigmoid_f(accr0[m][reg] + br0v);
      float rv1 = sigmoid_f(accr1[m][reg] + br1v);
      zk0[m][reg] = sigmoid_f(accz0[m][reg] + bz0v);
      zk1[m][reg] = sigmoid_f(accz1[m][reg] + bz1v);
      rhp[m][reg] = (unsigned int)f2bf(rv0 * bf2f((unsigned short)u0))
                  | ((unsigned int)f2bf(rv1 * bf2f((unsigned short)u1)) << 16);
    }
  }
  __syncthreads();   // (2) all stage-1 reads of A1 complete before in-place overwrite

#pragma unroll
  for (int m = 0; m < 4; ++m){
#pragma unroll
    for (int reg = 0; reg < 4; ++reg){
      const int row = m * 16 + lq * 4 + reg;
      const unsigned int swz = (unsigned)((row & 7) << 4);
      *(unsigned short*)(A1 + ((unsigned)(row * 512 + (128 + cb) * 2) ^ swz))      = (unsigned short)(rhp[m][reg] & 0xffffu);
      *(unsigned short*)(A1 + ((unsigned)(row * 512 + (128 + cb + 16) * 2) ^ swz)) = (unsigned short)(rhp[m][reg] >> 16);
    }
  }
  __syncthreads();   // (3) A1 now holds [x_tan | r*h_tan]

  // ---------- stage 2: [x_tan | r*h_tan] @ Wh, wave w -> cols [w*32, w*32+32) ----------
  const unsigned short* pwh = wp + 65536 + w * 8192;
  f32x4 ac0[4], ac1[4];
#pragma unroll
  for (int m = 0; m < 4; ++m){ ac0[m] = 0; ac1[m] = 0; }

#pragma unroll 2
  for (int kk = 0; kk < 8; ++kk){
    const bf16x8 b0 = *(const bf16x8*)(pwh + kk * 512 + l * 8);
    const bf16x8 b1 = *(const bf16x8*)(pwh + 4096 + kk * 512 + l * 8);
#pragma unroll
    for (int m = 0; m < 4; ++m){
      const int row = m * 16 + l15;
      unsigned int byte = (unsigned)(row * 512 + (kk * 32 + lq * 8) * 2) ^ (unsigned)((row & 7) << 4);
      const bf16x8 a = *(const bf16x8*)(A1 + byte);
      ac0[m] = __builtin_amdgcn_mfma_f32_16x16x32_bf16(a, b0, ac0[m], 0, 0, 0);
      ac1[m] = __builtin_amdgcn_mfma_f32_16x16x32_bf16(a, b1, ac1[m], 0, 0, 0);
    }
  }

  // ---------- epilogue 2: h_new_tan in regs ----------
  const float bh0v = bhp[cb], bh1v = bhp[cb + 16];
  f32x4 o0[4], o1[4];
#pragma unroll
  for (int m = 0; m < 4; ++m){
#pragma unroll
    for (int reg = 0; reg < 4; ++reg){
      float htld0 = tanh_f(ac0[m][reg] + bh0v);
      float htld1 = tanh_f(ac1[m][reg] + bh1v);
      float ht0 = bf2f((unsigned short)(htp[m][reg] & 0xffffu));
      float ht1 = bf2f((unsigned short)(htp[m][reg] >> 16));
      float z0 = zk0[m][reg], z1 = zk1[m][reg];
      o0[m][reg] = (1.f - z0) * ht0 + z0 * htld0;
      o1[m][reg] = (1.f - z1) * ht1 + z1 * htld1;
    }
  }
  __syncthreads();   // (4) all stage-2 reads of A1 complete before P overlay

  // ---------- row sumsq: 16-lane shuffle reduce + cross-wave partials ----------
#pragma unroll
  for (int m = 0; m < 4; ++m){
#pragma unroll
    for (int reg = 0; reg < 4; ++reg){
      const int row = m * 16 + lq * 4 + reg;
      float s = o0[m][reg] * o0[m][reg] + o1[m][reg] * o1[m][reg];
      s += __shfl_xor(s, 1, 16);
      s += __shfl_xor(s, 2, 16);
      s += __shfl_xor(s, 4, 16);
      s += __shfl_xor(s, 8, 16);
      if (l15 == 0) P[row * 4 + w] = s;
    }
  }
  __syncthreads();   // (5) partials visible

  // ---------- final: expmap0 + proj, store from registers ----------
#pragma unroll
  for (int m = 0; m < 4; ++m){
#pragma unroll
    for (int reg = 0; reg < 4; ++reg){
      const int row = m * 16 + lq * 4 + reg;
      const f32x4 p4 = *(const f32x4*)(P + row * 4);     // broadcast read (same addr per 16 lanes)
      float ss = p4[0] + p4[1] + p4[2] + p4[3];
      float n = sqrtf(ss);
      float sc = 1.f;
      if (n > 1e-20f){
        float th = tanh_f(n);
        th = fminf(th, 0.99999f);          // proj: maxnorm = 1 - 1e-5
        sc = th / n;
      }
      float* orow = out + (row0 + row) * D;
      orow[cb]      = o0[m][reg] * sc;
      orow[cb + 16] = o1[m][reg] * sc;
    }
  }
}

extern "C" void kernel_launch(void* const* d_in, const int* in_sizes, int n_in,
                              void* d_out, int out_size, void* d_ws, size_t ws_size,
                              hipStream_t stream)
{
  const float* x   = (const float*)d_in[0];
  const float* h   = (const float*)d_in[1];
  const float* Wr  = (const float*)d_in[2];
  const float* brp = (const float*)d_in[3];
  const float* Wz  = (const float*)d_in[4];
  const float* bzp = (const float*)d_in[5];
  const float* Wh  = (const float*)d_in[6];
  const float* bhp = (const float*)d_in[7];
  unsigned short* wsp = (unsigned short*)d_ws;   // 3 * 32768 bf16 = 192KB packed weights

  prep_weights<<<192, 64, 0, stream>>>(Wr, Wz, Wh, wsp);
  gru_fused<<<262144 / BM, 256, 0, stream>>>(x, h, brp, bzp, bhp, wsp, (float*)d_out);
}

// Round 3
// 147.791 us; speedup vs baseline: 1.2531x; 1.2531x over previous
//
#include <hip/hip_runtime.h>
#include <hip/hip_bf16.h>

typedef __attribute__((ext_vector_type(4))) float f32x4;
typedef __attribute__((ext_vector_type(8))) short bf16x8;
typedef __attribute__((ext_vector_type(4))) short bf16x4;
typedef __attribute__((ext_vector_type(2))) unsigned int u32x2;

#define D 128
#define BM 64

__device__ __forceinline__ unsigned short f2bf(float f){
  union { float f; unsigned int i; } c; c.f = f;
  unsigned int i = c.i;
  i += 0x7fffu + ((i >> 16) & 1u);   // round-to-nearest-even
  return (unsigned short)(i >> 16);
}
__device__ __forceinline__ float bf2f(unsigned short u){
  union { float f; unsigned int i; } c; c.i = ((unsigned int)u) << 16; return c.f;
}
// pack two floats -> 2x bf16 in one u32 (v_cvt_pk_bf16_f32)
__device__ __forceinline__ unsigned int pk2(float a, float b){
  __hip_bfloat162 t = __float22bfloat162_rn(make_float2(a, b));
  return *reinterpret_cast<unsigned int*>(&t);
}
__device__ __forceinline__ float sigmoid_f(float t){
  return 1.0f / (1.0f + __expf(-t));
}
__device__ __forceinline__ float tanh_f(float t){
  t = fminf(fmaxf(t, -20.0f), 20.0f);
  float e = __expf(2.0f * t);
  return (e - 1.0f) / (e + 1.0f);
}

// Pack W[k=256][n=128] fp32 -> bf16 MFMA fragments:
// frag f = nf*8+kk ; lane l holds col = nf*16+(l&15), k = kk*32+(l>>4)*8+j (j=0..7)
// Used as the A-operand (A = W^T slice): lane l = outcol l&15, 8 consecutive k.
__global__ void prep_weights(const float* __restrict__ Wr, const float* __restrict__ Wz,
                             const float* __restrict__ Wh, unsigned short* __restrict__ wp)
{
  int w = blockIdx.x >> 6;          // 0:Wr 1:Wz 2:Wh
  int f = blockIdx.x & 63;          // nf*8 + kk
  int l = threadIdx.x;              // 0..63
  const float* src = (w == 0) ? Wr : ((w == 1) ? Wz : Wh);
  int nf = f >> 3, kk = f & 7;
  int col = nf * 16 + (l & 15);
  int k0  = kk * 32 + (l >> 4) * 8;
  unsigned short* dst = wp + w * 32768 + (f * 64 + l) * 8;
#pragma unroll
  for (int j = 0; j < 8; ++j)
    dst[j] = f2bf(src[(k0 + j) * D + col]);
}

__global__ __launch_bounds__(256, 4) void gru_fused(
    const float* __restrict__ x, const float* __restrict__ h,
    const float* __restrict__ brp, const float* __restrict__ bzp, const float* __restrict__ bhp,
    const unsigned short* __restrict__ wp, float* __restrict__ out)
{
  // A1: xh bf16 [64 rows][256 k] XOR-swizzled (32KB). r*h_tan overwrites the h-half in place.
  // P: f32 row-sumsq partials [64][4] (1KB), overlays A1 after all stage-2 reads.
  __shared__ __align__(16) unsigned char A1[BM * 512];
  float* P = (float*)A1;

  const int tid = threadIdx.x;
  const int w   = tid >> 6;
  const int l   = tid & 63;
  const int l15 = l & 15;
  const int lq  = l >> 4;
  const size_t row0 = (size_t)blockIdx.x * BM;

  // ---------- phase 1: logmap0(x), logmap0(h) -> A1 bf16 (swizzled) ----------
  {
    const int row = tid >> 2;
    const int q   = tid & 3;
    const f32x4* xr = (const f32x4*)(x + (row0 + row) * D);
    const f32x4* hr = (const f32x4*)(h + (row0 + row) * D);
    f32x4 v[8];
    float ss = 0.f;
#pragma unroll
    for (int j = 0; j < 8; ++j){
      v[j] = xr[j * 4 + q];
      ss += v[j][0]*v[j][0] + v[j][1]*v[j][1] + v[j][2]*v[j][2] + v[j][3]*v[j][3];
    }
    ss += __shfl_xor(ss, 1, 64);
    ss += __shfl_xor(ss, 2, 64);
    float n = sqrtf(ss);
    float s = (n > 1e-20f) ? (0.5f * __logf((1.f + n) / (1.f - n)) / n) : 1.f;
#pragma unroll
    for (int j = 0; j < 8; ++j){
      unsigned int byte = (unsigned)(row * 512 + (4 * j + q) * 8) ^ (unsigned)((row & 7) << 4);
      u32x2 pk; pk[0] = pk2(v[j][0] * s, v[j][1] * s); pk[1] = pk2(v[j][2] * s, v[j][3] * s);
      *(u32x2*)(A1 + byte) = pk;
    }
    ss = 0.f;
#pragma unroll
    for (int j = 0; j < 8; ++j){
      v[j] = hr[j * 4 + q];
      ss += v[j][0]*v[j][0] + v[j][1]*v[j][1] + v[j][2]*v[j][2] + v[j][3]*v[j][3];
    }
    ss += __shfl_xor(ss, 1, 64);
    ss += __shfl_xor(ss, 2, 64);
    n = sqrtf(ss);
    s = (n > 1e-20f) ? (0.5f * __logf((1.f + n) / (1.f - n)) / n) : 1.f;
#pragma unroll
    for (int j = 0; j < 8; ++j){
      unsigned int byte = (unsigned)(row * 512 + 256 + (4 * j + q) * 8) ^ (unsigned)((row & 7) << 4);
      u32x2 pk; pk[0] = pk2(v[j][0] * s, v[j][1] * s); pk[1] = pk2(v[j][2] * s, v[j][3] * s);
      *(u32x2*)(A1 + byte) = pk;
    }
  }
  __syncthreads();   // (1) A1 populated

  // ---------- stage 1: D = mfma(W^T frag, xh^T frag) ----------
  // wave w -> outcols [w*32, w*32+32) (ntiles t=0,1), all 64 rows (m=0..3).
  // lane holds: row = m*16+l15, outcols c0(t)+{0..3}, c0(t) = w*32+t*16+lq*4.
  const unsigned short* pwr = wp + w * 8192;
  const unsigned short* pwz = wp + 32768 + w * 8192;

  f32x4 ar0[4], ar1[4], az0[4], az1[4];
#pragma unroll
  for (int m = 0; m < 4; ++m){ ar0[m] = 0; ar1[m] = 0; az0[m] = 0; az1[m] = 0; }

#pragma unroll 2
  for (int kk = 0; kk < 8; ++kk){
    const bf16x8 wr0 = *(const bf16x8*)(pwr + kk * 512 + l * 8);
    const bf16x8 wr1 = *(const bf16x8*)(pwr + 4096 + kk * 512 + l * 8);
    const bf16x8 wz0 = *(const bf16x8*)(pwz + kk * 512 + l * 8);
    const bf16x8 wz1 = *(const bf16x8*)(pwz + 4096 + kk * 512 + l * 8);
#pragma unroll
    for (int m = 0; m < 4; ++m){
      const int row = m * 16 + l15;
      unsigned int byte = (unsigned)(row * 512 + (kk * 32 + lq * 8) * 2) ^ (unsigned)((row & 7) << 4);
      const bf16x8 b = *(const bf16x8*)(A1 + byte);
      ar0[m] = __builtin_amdgcn_mfma_f32_16x16x32_bf16(wr0, b, ar0[m], 0, 0, 0);
      ar1[m] = __builtin_amdgcn_mfma_f32_16x16x32_bf16(wr1, b, ar1[m], 0, 0, 0);
      az0[m] = __builtin_amdgcn_mfma_f32_16x16x32_bf16(wz0, b, az0[m], 0, 0, 0);
      az1[m] = __builtin_amdgcn_mfma_f32_16x16x32_bf16(wz1, b, az1[m], 0, 0, 0);
    }
  }

  // ---------- epilogue 1: r,z; rh packed; ht stashed ----------
  const int c00 = w * 32 + lq * 4;
  const int c01 = c00 + 16;
  const f32x4 brv0 = *(const f32x4*)(brp + c00);
  const f32x4 brv1 = *(const f32x4*)(brp + c01);
  const f32x4 bzv0 = *(const f32x4*)(bzp + c00);
  const f32x4 bzv1 = *(const f32x4*)(bzp + c01);

  f32x4 zk0[4], zk1[4];
  u32x2 htp0[4], htp1[4];   // packed bf16 h_tan, 4 consecutive cols
  u32x2 rhp0[4], rhp1[4];   // packed bf16 r*h_tan
#pragma unroll
  for (int m = 0; m < 4; ++m){
    const int row = m * 16 + l15;
    const unsigned int swz = (unsigned)((row & 7) << 4);
    const bf16x4 h40 = *(const bf16x4*)(A1 + ((unsigned)(row * 512 + (128 + c00) * 2) ^ swz));
    const bf16x4 h41 = *(const bf16x4*)(A1 + ((unsigned)(row * 512 + (128 + c01) * 2) ^ swz));
    htp0[m] = *(const u32x2*)&h40;
    htp1[m] = *(const u32x2*)&h41;
    float rh0[4], rh1[4];
#pragma unroll
    for (int reg = 0; reg < 4; ++reg){
      float r0 = sigmoid_f(ar0[m][reg] + brv0[reg]);
      float r1 = sigmoid_f(ar1[m][reg] + brv1[reg]);
      zk0[m][reg] = sigmoid_f(az0[m][reg] + bzv0[reg]);
      zk1[m][reg] = sigmoid_f(az1[m][reg] + bzv1[reg]);
      rh0[reg] = r0 * bf2f((unsigned short)h40[reg]);
      rh1[reg] = r1 * bf2f((unsigned short)h41[reg]);
    }
    rhp0[m][0] = pk2(rh0[0], rh0[1]); rhp0[m][1] = pk2(rh0[2], rh0[3]);
    rhp1[m][0] = pk2(rh1[0], rh1[1]); rhp1[m][1] = pk2(rh1[2], rh1[3]);
  }
  __syncthreads();   // (2) all stage-1 LDS reads complete before in-place overwrite

#pragma unroll
  for (int m = 0; m < 4; ++m){
    const int row = m * 16 + l15;
    const unsigned int swz = (unsigned)((row & 7) << 4);
    *(u32x2*)(A1 + ((unsigned)(row * 512 + (128 + c00) * 2) ^ swz)) = rhp0[m];
    *(u32x2*)(A1 + ((unsigned)(row * 512 + (128 + c01) * 2) ^ swz)) = rhp1[m];
  }
  __syncthreads();   // (3) A1 now holds [x_tan | r*h_tan]

  // ---------- stage 2: [x_tan | r*h_tan] @ Wh ----------
  const unsigned short* pwh = wp + 65536 + w * 8192;
  f32x4 ah0[4], ah1[4];
#pragma unroll
  for (int m = 0; m < 4; ++m){ ah0[m] = 0; ah1[m] = 0; }

#pragma unroll 2
  for (int kk = 0; kk < 8; ++kk){
    const bf16x8 wh0 = *(const bf16x8*)(pwh + kk * 512 + l * 8);
    const bf16x8 wh1 = *(const bf16x8*)(pwh + 4096 + kk * 512 + l * 8);
#pragma unroll
    for (int m = 0; m < 4; ++m){
      const int row = m * 16 + l15;
      unsigned int byte = (unsigned)(row * 512 + (kk * 32 + lq * 8) * 2) ^ (unsigned)((row & 7) << 4);
      const bf16x8 b = *(const bf16x8*)(A1 + byte);
      ah0[m] = __builtin_amdgcn_mfma_f32_16x16x32_bf16(wh0, b, ah0[m], 0, 0, 0);
      ah1[m] = __builtin_amdgcn_mfma_f32_16x16x32_bf16(wh1, b, ah1[m], 0, 0, 0);
    }
  }

  // ---------- epilogue 2: h_new_tan in regs ----------
  const f32x4 bhv0 = *(const f32x4*)(bhp + c00);
  const f32x4 bhv1 = *(const f32x4*)(bhp + c01);
  f32x4 o0[4], o1[4];
#pragma unroll
  for (int m = 0; m < 4; ++m){
#pragma unroll
    for (int reg = 0; reg < 4; ++reg){
      float htld0 = tanh_f(ah0[m][reg] + bhv0[reg]);
      float htld1 = tanh_f(ah1[m][reg] + bhv1[reg]);
      float ht0 = bf2f((unsigned short)(htp0[m][reg >> 1] >> ((reg & 1) * 16)));
      float ht1 = bf2f((unsigned short)(htp1[m][reg >> 1] >> ((reg & 1) * 16)));
      float z0 = zk0[m][reg], z1 = zk1[m][reg];
      o0[m][reg] = (1.f - z0) * ht0 + z0 * htld0;
      o1[m][reg] = (1.f - z1) * ht1 + z1 * htld1;
    }
  }
  __syncthreads();   // (4) all stage-2 LDS reads done before P overlay

  // ---------- row sumsq: lane has 8 cols of its row; reduce across lq lanes ----------
#pragma unroll
  for (int m = 0; m < 4; ++m){
    const int row = m * 16 + l15;
    float s = 0.f;
#pragma unroll
    for (int reg = 0; reg < 4; ++reg)
      s += o0[m][reg]*o0[m][reg] + o1[m][reg]*o1[m][reg];
    s += __shfl_xor(s, 16, 64);
    s += __shfl_xor(s, 32, 64);
    if (lq == 0) P[row * 4 + w] = s;
  }
  __syncthreads();   // (5) partials visible

  // ---------- final: expmap0 + proj, f32x4 stores (wave fills full 128B line/row) ----------
#pragma unroll
  for (int m = 0; m < 4; ++m){
    const int row = m * 16 + l15;
    const f32x4 p4 = *(const f32x4*)(P + row * 4);   // broadcast within row group
    float ss = p4[0] + p4[1] + p4[2] + p4[3];
    float n = sqrtf(ss);
    float sc = 1.f;
    if (n > 1e-20f){
      float th = tanh_f(n);
      th = fminf(th, 0.99999f);          // proj: maxnorm = 1 - 1e-5
      sc = th / n;
    }
    float* orow = out + (row0 + row) * D;
    f32x4 st0 = o0[m] * sc;
    f32x4 st1 = o1[m] * sc;
    *(f32x4*)(orow + c00) = st0;
    *(f32x4*)(orow + c01) = st1;
  }
}

extern "C" void kernel_launch(void* const* d_in, const int* in_sizes, int n_in,
                              void* d_out, int out_size, void* d_ws, size_t ws_size,
                              hipStream_t stream)
{
  const float* x   = (const float*)d_in[0];
  const float* h   = (const float*)d_in[1];
  const float* Wr  = (const float*)d_in[2];
  const float* brp = (const float*)d_in[3];
  const float* Wz  = (const float*)d_in[4];
  const float* bzp = (const float*)d_in[5];
  const float* Wh  = (const float*)d_in[6];
  const float* bhp = (const float*)d_in[7];
  unsigned short* wsp = (unsigned short*)d_ws;   // 3 * 32768 bf16 = 192KB packed weights

  prep_weights<<<192, 64, 0, stream>>>(Wr, Wz, Wh, wsp);
  gru_fused<<<262144 / BM, 256, 0, stream>>>(x, h, brp, bzp, bhp, wsp, (float*)d_out);
}